// Round 8
// baseline (433.370 us; speedup 1.0000x reference)
//
#include <hip/hip_runtime.h>

// NormalizedCrossEntropy: logits [8192,10000] f32, targets [8192] int32 -> scalar f32
//   ce_i    = lse_i - logits_i[t_i]
//   sum_ce_i= C*lse_i - sum_k logits_ik
//   out     = mean_i( ce_i / (sum_ce_i + 1e-8) )
//
// Memory-bound: 327.7 MB read-once -> floor ~52us @ 6.3 TB/s.
// Persistent grid (G11): 2048 blocks x 4 rows each = 8 blocks/CU x 4 waves
// = 32 waves/CU (max occupancy). Per block: prefetch 4 target logits
// (uniform scalar loads, latency hidden under stream), stream 4x40KB rows
// with fully-unrolled float4 loads and per-row register accumulators
// (static-indexed), single barrier + epilogue at the end.

#define NB_ROWS 8192
#define NC_COLS 10000
#define NC_VEC4 (NC_COLS / 4)       // 2500, exact
#define ROWS_PER_BLK 4
#define NBLK (NB_ROWS / ROWS_PER_BLK)  // 2048
#define EPSV 1e-8f

__global__ __launch_bounds__(256) void nce_row_kernel(const float* __restrict__ logits,
                                                      const int* __restrict__ targets,
                                                      float* __restrict__ row_ratio) {
    const int tid  = threadIdx.x;
    const int row0 = blockIdx.x * ROWS_PER_BLK;
    const float* __restrict__ rp0 = logits + (size_t)row0 * NC_COLS;

    float se[ROWS_PER_BLK];   // sum of exp, per row (static-indexed only)
    float sx[ROWS_PER_BLK];   // sum of x,   per row
    float tgt[ROWS_PER_BLK];  // target logit, per row (uniform, prefetched)

    // Prefetch target logits first: uniform scalar loads whose latency
    // hides under the 160KB main stream below.
    #pragma unroll
    for (int r = 0; r < ROWS_PER_BLK; ++r) {
        se[r] = 0.0f;
        sx[r] = 0.0f;
        tgt[r] = rp0[(size_t)r * NC_COLS + targets[row0 + r]];
    }

    // Main stream: 4 rows x 2500 float4 / 256 threads, no barriers.
    #pragma unroll
    for (int r = 0; r < ROWS_PER_BLK; ++r) {
        const float4* __restrict__ rp4 =
            reinterpret_cast<const float4*>(rp0 + (size_t)r * NC_COLS);
        #pragma unroll
        for (int k = 0; k < 10; ++k) {
            const int idx = tid + (k << 8);
            if (idx < NC_VEC4) {   // 2500 = 9*256 + 196 (k=9 partial)
                const float4 v = rp4[idx];
                sx[r] += (v.x + v.y) + (v.z + v.w);
                se[r] += (__expf(v.x) + __expf(v.y)) + (__expf(v.z) + __expf(v.w));
            }
        }
    }

    // Epilogue: 4 wave64 shuffle reductions + one LDS cross-wave pass.
    __shared__ float s_exp[ROWS_PER_BLK][4];
    __shared__ float s_x[ROWS_PER_BLK][4];
    const int wave = tid >> 6;

    #pragma unroll
    for (int r = 0; r < ROWS_PER_BLK; ++r) {
        float e = se[r], x = sx[r];
        #pragma unroll
        for (int off = 32; off > 0; off >>= 1) {
            e += __shfl_down(e, off);
            x += __shfl_down(x, off);
        }
        if ((tid & 63) == 0) { s_exp[r][wave] = e; s_x[r][wave] = x; }
    }
    __syncthreads();

    if (tid == 0) {
        #pragma unroll
        for (int r = 0; r < ROWS_PER_BLK; ++r) {
            const float e   = (s_exp[r][0] + s_exp[r][1]) + (s_exp[r][2] + s_exp[r][3]);
            const float x   = (s_x[r][0]   + s_x[r][1])   + (s_x[r][2]   + s_x[r][3]);
            const float lse = __logf(e);
            const float ce  = lse - tgt[r];
            const float sum_ce = (float)NC_COLS * lse - x;
            row_ratio[row0 + r] = ce / (sum_ce + EPSV);
        }
    }
}

__global__ __launch_bounds__(256) void nce_reduce_kernel(const float* __restrict__ row_ratio,
                                                         float* __restrict__ out) {
    const int tid = threadIdx.x;
    float s = 0.0f;
    #pragma unroll
    for (int k = 0; k < NB_ROWS / 256; ++k) s += row_ratio[tid + (k << 8)];

    #pragma unroll
    for (int off = 32; off > 0; off >>= 1) s += __shfl_down(s, off);

    __shared__ float sw[4];
    if ((tid & 63) == 0) sw[tid >> 6] = s;
    __syncthreads();

    if (tid == 0) out[0] = ((sw[0] + sw[1]) + (sw[2] + sw[3])) * (1.0f / (float)NB_ROWS);
}

extern "C" void kernel_launch(void* const* d_in, const int* in_sizes, int n_in,
                              void* d_out, int out_size, void* d_ws, size_t ws_size,
                              hipStream_t stream) {
    const float* logits  = (const float*)d_in[0];
    const int*   targets = (const int*)d_in[1];
    float* out = (float*)d_out;
    float* row_ratio = (float*)d_ws;   // 8192 * 4 B = 32 KiB scratch

    nce_row_kernel<<<NBLK, 256, 0, stream>>>(logits, targets, row_ratio);
    nce_reduce_kernel<<<1, 256, 0, stream>>>(row_ratio, out);
}